// Round 1
// baseline (2930.610 us; speedup 1.0000x reference)
//
#include <hip/hip_runtime.h>
#include <math.h>

// MoE gate: logits = h(16384x4096) @ w(64x4096)^T + bias; softmax; top-2;
// renormalize. Output: [topk_w (16384x2 f32) ; topk_idx (16384x2, stored as f32)].
//
// f32 VALU GEMM, N=64 held entirely in per-thread accumulators.
// WG = 512 threads = 32 rows x 16 k-slices (slices interleaved at float4
// granularity so each row's 16 threads load 256 contiguous bytes of h).
// Weight streamed through LDS in 256-float k-chunks (64 KB -> 2 WG/CU,
// 4 waves/SIMD at <=128 VGPR). Epilogue fused: shfl_xor reduction over the
// 16 slice-lanes, then top-2 scan; softmax Z cancels in topk_w so only the
// top-2 logits are needed: w1 = 1/(1+exp(l2-l1)), w2 = 1-w1.

#define HIDDEN   4096
#define NSHARD   64
#define B_ROWS   16384
#define ROWS_WG  32
#define SLICES   16
#define NTHR     (ROWS_WG * SLICES)     // 512
#define KC       256                    // k floats staged per chunk
#define NCHUNK   (HIDDEN / KC)          // 16
#define ISTEPS   (KC / (SLICES * 4))    // 4

__global__ __launch_bounds__(NTHR, 4)
void gate_kernel(const float* __restrict__ h,
                 const float* __restrict__ w,
                 const float* __restrict__ bias,
                 float* __restrict__ out)
{
    __shared__ float lw[NSHARD][KC];    // 64 KB

    const int tid = threadIdx.x;
    const int r   = tid >> 4;           // 0..31  row within WG
    const int s   = tid & 15;           // 0..15  k-slice
    const int row = blockIdx.x * ROWS_WG + r;

    const float* __restrict__ hrow = h + (size_t)row * HIDDEN;

    float acc[NSHARD];
#pragma unroll
    for (int e = 0; e < NSHARD; ++e) acc[e] = 0.0f;

    for (int c = 0; c < NCHUNK; ++c) {
        const int k0 = c * KC;
        __syncthreads();                // protect LDS from prior-chunk readers
        // stage w[0..63][k0..k0+KC) -> LDS, coalesced float4
#pragma unroll
        for (int t = 0; t < (NSHARD * KC / 4) / NTHR; ++t) {   // 8 float4/thread
            const int idx = t * NTHR + tid;    // float4 index in [64][KC/4]
            const int e   = idx >> 6;          // KC/4 == 64
            const int kq  = idx & 63;
            const float4 v = *(const float4*)(w + (size_t)e * HIDDEN + k0 + kq * 4);
            *(float4*)(&lw[e][kq * 4]) = v;
        }
        __syncthreads();

#pragma unroll
        for (int i = 0; i < ISTEPS; ++i) {
            const int kin = i * (SLICES * 4) + s * 4;
            const float4 hv = *(const float4*)(hrow + k0 + kin);
#pragma unroll
            for (int e = 0; e < NSHARD; ++e) {
                const float4 wv = *(const float4*)(&lw[e][kin]);
                acc[e] = fmaf(hv.x, wv.x, acc[e]);
                acc[e] = fmaf(hv.y, wv.y, acc[e]);
                acc[e] = fmaf(hv.z, wv.z, acc[e]);
                acc[e] = fmaf(hv.w, wv.w, acc[e]);
            }
        }
    }

    // reduce the 16 k-slice partials: slice lanes are contiguous within the
    // wave (lane = ..r[1:0]..s[3:0]) so xor-masks 1,2,4,8 stay in-group.
#pragma unroll
    for (int m = 1; m < SLICES; m <<= 1) {
#pragma unroll
        for (int e = 0; e < NSHARD; ++e)
            acc[e] += __shfl_xor(acc[e], m, 64);
    }

    // top-2 scan over 64 logits (+bias). Strict '>' => first occurrence wins,
    // matching lax.top_k tie-breaking. All threads compute; s==0 writes.
    float m1 = -INFINITY, m2 = -INFINITY;
    int   i1 = 0, i2 = 0;
#pragma unroll
    for (int e = 0; e < NSHARD; ++e) {
        const float v = acc[e] + bias[e];
        if (v > m1)      { m2 = m1; i2 = i1; m1 = v; i1 = e; }
        else if (v > m2) { m2 = v;  i2 = e; }
    }

    if (s == 0) {
        // topk_w = p_i/(p1+p2); softmax Z cancels: only l1,l2 matter.
        const float ed  = expf(m2 - m1);        // <= 1
        const float inv = 1.0f / (1.0f + ed);
        out[2 * row + 0] = inv;
        out[2 * row + 1] = ed * inv;
        float* oidx = out + 2 * B_ROWS;         // second tuple element
        oidx[2 * row + 0] = (float)i1;
        oidx[2 * row + 1] = (float)i2;
    }
}

extern "C" void kernel_launch(void* const* d_in, const int* in_sizes, int n_in,
                              void* d_out, int out_size, void* d_ws, size_t ws_size,
                              hipStream_t stream)
{
    const float* h    = (const float*)d_in[0];   // 16384*4096 f32
    const float* wt   = (const float*)d_in[1];   // 64*4096 f32
    const float* bias = (const float*)d_in[2];   // 64 f32
    float* out = (float*)d_out;                  // 65536 f32 (w ; idx)

    gate_kernel<<<dim3(B_ROWS / ROWS_WG), dim3(NTHR), 0, stream>>>(h, wt, bias, out);
}

// Round 2
// 529.747 us; speedup vs baseline: 5.5321x; 5.5321x over previous
//
#include <hip/hip_runtime.h>
#include <math.h>

// MoE gate: logits = h(16384x4096) @ w(64x4096)^T + bias; softmax; top-2;
// renormalize. Output: [topk_w (16384x2 f32) ; topk_idx (16384x2 as f32)].
//
// Round-1 failure: acc[64]/thread spilled to scratch (VGPR_Count=64,
// WRITE_SIZE=5 GB). Fix: thread tile = 4 rows x 4 shards (acc[16] in VGPRs).
//
// WG = 256 threads = 16 shard-groups(g) x 4 k-slices(ks) x 4 row-groups(rg).
//   lane = g + 16*ks (waves aligned to rg) -> ks-reduce via shfl_xor 16,32;
//   top-2 merge across g via shfl_xor 1,2,4,8.
// Weight streamed through LDS in 128-float k-chunks, layout lw[j][g][132]:
//   pad 132 => per-instruction banks = (g*4+step*4)%32 -> 8 distinct quads,
//   full-rate b128 (row-major 128 would land all 64 lanes on one quad).
// Per k-step per thread: 4 global h float4 + 4 LDS b128 -> 64 FMA:
//   LDS pipe ~37% of VALU, VMEM 1:27 -> VALU-bound by construction.

#define HIDDEN   4096
#define NSHARD   64
#define B_ROWS   16384
#define WGT      256
#define ROWS_WG  16
#define KC       128
#define NCHUNK   (HIDDEN / KC)   // 32
#define KCP      132             // padded k-stride (floats) in LDS
#define LDSF     (4 * 16 * KCP)  // 8448 floats = 33 KB

__global__ __launch_bounds__(WGT, 4)
void gate_kernel(const float* __restrict__ h,
                 const float* __restrict__ w,
                 const float* __restrict__ bias,
                 float* __restrict__ out)
{
    __shared__ float lw[LDSF];

    const int tid = threadIdx.x;
    const int g   = tid & 15;          // shard group: shards g*4 + j, j=0..3
    const int ks  = (tid >> 4) & 3;    // k-slice (32 floats of each chunk)
    const int rg  = tid >> 6;          // wave id = row group (4 rows)
    const int row0 = blockIdx.x * ROWS_WG + rg * 4;

    const float* __restrict__ hbase = h + (size_t)row0 * HIDDEN;

    float acc[4][4];                   // [row][shard j] — registers only
#pragma unroll
    for (int r = 0; r < 4; ++r)
#pragma unroll
        for (int j = 0; j < 4; ++j) acc[r][j] = 0.0f;

    for (int c = 0; c < NCHUNK; ++c) {
        __syncthreads();               // prior-chunk readers done
        // ---- stage w[0..63][c*128 .. +128) -> LDS (grouped, padded) ----
#pragma unroll
        for (int t = 0; t < 8; ++t) {
            const int idx = t * WGT + tid;        // 0..2047 float4 slots
            const int kq  = idx & 31;             // float4 within k-chunk
            const int e   = idx >> 5;             // shard 0..63
            const float4 v = *(const float4*)(w + (size_t)e * HIDDEN + c * KC + kq * 4);
            const int j  = e & 3;
            const int gg = e >> 2;
            *(float4*)(lw + j * (16 * KCP) + gg * KCP + kq * 4) = v;
        }
        __syncthreads();

        // ---- compute: 8 float4 steps over this thread's 32-float k-slice ----
#pragma unroll
        for (int step = 0; step < 8; ++step) {
            const int kin = c * KC + ks * 32 + step * 4;
            float4 hv[4];
#pragma unroll
            for (int r = 0; r < 4; ++r)
                hv[r] = *(const float4*)(hbase + (size_t)r * HIDDEN + kin);
#pragma unroll
            for (int j = 0; j < 4; ++j) {
                const float4 wv = *(const float4*)(lw + j * (16 * KCP) + g * KCP
                                                   + ks * 32 + step * 4);
#pragma unroll
                for (int r = 0; r < 4; ++r) {
                    acc[r][j] = fmaf(hv[r].x, wv.x, acc[r][j]);
                    acc[r][j] = fmaf(hv[r].y, wv.y, acc[r][j]);
                    acc[r][j] = fmaf(hv[r].z, wv.z, acc[r][j]);
                    acc[r][j] = fmaf(hv[r].w, wv.w, acc[r][j]);
                }
            }
        }
    }

    // ---- reduce over the 4 k-slices (lane bits 4,5) ----
#pragma unroll
    for (int m = 16; m <= 32; m <<= 1)
#pragma unroll
        for (int r = 0; r < 4; ++r)
#pragma unroll
            for (int j = 0; j < 4; ++j)
                acc[r][j] += __shfl_xor(acc[r][j], m, 64);

    // ---- bias + per-thread top-2 over 4 shards (ascending j: first-occurrence) ----
    const float4 bv = *(const float4*)(bias + g * 4);
    float m1[4], m2[4];
    int   i1[4], i2[4];
#pragma unroll
    for (int r = 0; r < 4; ++r) {
        float v0 = acc[r][0] + bv.x, v1 = acc[r][1] + bv.y;
        float v2 = acc[r][2] + bv.z, v3 = acc[r][3] + bv.w;
        float a1 = v0, a2 = -INFINITY; int b1 = g * 4, b2 = 0;
        if (v1 > a1)      { a2 = a1; b2 = b1; a1 = v1; b1 = g * 4 + 1; }
        else              { a2 = v1; b2 = g * 4 + 1; }
        if (v2 > a1)      { a2 = a1; b2 = b1; a1 = v2; b1 = g * 4 + 2; }
        else if (v2 > a2) { a2 = v2; b2 = g * 4 + 2; }
        if (v3 > a1)      { a2 = a1; b2 = b1; a1 = v3; b1 = g * 4 + 3; }
        else if (v3 > a2) { a2 = v3; b2 = g * 4 + 3; }
        m1[r] = a1; i1[r] = b1; m2[r] = a2; i2[r] = b2;
    }

    // ---- merge top-2 across the 16 shard-groups (lane bits 0..3) ----
#pragma unroll
    for (int m = 1; m <= 8; m <<= 1) {
#pragma unroll
        for (int r = 0; r < 4; ++r) {
            const float o1 = __shfl_xor(m1[r], m, 64);
            const int   q1 = __shfl_xor(i1[r], m, 64);
            const float o2 = __shfl_xor(m2[r], m, 64);
            const int   q2 = __shfl_xor(i2[r], m, 64);
            const bool take = (o1 > m1[r]) || (o1 == m1[r] && q1 < i1[r]);
            const float w1 = take ? o1 : m1[r]; const int w1i = take ? q1 : i1[r];
            const float l1 = take ? m1[r] : o1; const int l1i = take ? i1[r] : q1;
            const float s2 = take ? o2 : m2[r]; const int s2i = take ? q2 : i2[r];
            const bool t2 = (l1 > s2) || (l1 == s2 && l1i < s2i);
            m1[r] = w1; i1[r] = w1i;
            m2[r] = t2 ? l1 : s2; i2[r] = t2 ? l1i : s2i;
        }
    }

    // ---- write: softmax Z cancels; w1 = 1/(1+e^{l2-l1}), w2 = 1-w1 ----
    if ((tid & 63) == 0) {
        float* __restrict__ oidx = out + 2 * B_ROWS;
#pragma unroll
        for (int r = 0; r < 4; ++r) {
            const int row = row0 + r;
            const float ed  = expf(m2[r] - m1[r]);   // <= 1
            const float inv = 1.0f / (1.0f + ed);
            out[2 * row + 0] = inv;
            out[2 * row + 1] = ed * inv;
            oidx[2 * row + 0] = (float)i1[r];
            oidx[2 * row + 1] = (float)i2[r];
        }
    }
}

extern "C" void kernel_launch(void* const* d_in, const int* in_sizes, int n_in,
                              void* d_out, int out_size, void* d_ws, size_t ws_size,
                              hipStream_t stream)
{
    const float* h    = (const float*)d_in[0];
    const float* wt   = (const float*)d_in[1];
    const float* bias = (const float*)d_in[2];
    float* out = (float*)d_out;

    gate_kernel<<<dim3(B_ROWS / ROWS_WG), dim3(WGT), 0, stream>>>(h, wt, bias, out);
}